// Round 9
// baseline (413.123 us; speedup 1.0000x reference)
//
#include <hip/hip_runtime.h>
#include <hip/hip_bf16.h>

// ---------------------------------------------------------------------------
// MultiheadAttention fused pipeline for MI355X (gfx950)
// B=2, S=S'=2048, H=16, D_MODEL=1024, dk=dv=64
// outputs: out [2,2048,1024] fp32, attn [2,16,2048,2048] fp32 (concat in d_out)
// ---------------------------------------------------------------------------

typedef __bf16 bf16x8 __attribute__((ext_vector_type(8)));
typedef __bf16 bf16x4 __attribute__((ext_vector_type(4)));
typedef float  f32x4  __attribute__((ext_vector_type(4)));
typedef float  f32x16 __attribute__((ext_vector_type(16)));

#define NUM_HEAD 16
#define SEQ 2048
#define DMODEL 1024
#define DK 64
#define MROWS 4096      // B*S
#define LOG2E 1.44269504088896340736f

__device__ __forceinline__ void gload_lds16(const void* g, void* l) {
    __builtin_amdgcn_global_load_lds((const __attribute__((address_space(1))) void*)g,
                                     (__attribute__((address_space(3))) void*)l, 16, 0, 0);
}

// ---------------------------------------------------------------------------
// Fused LayerNorm(query)->bf16  +  all fp32->bf16 casts, one dispatch.
// blocks [0,4096): LN row; blocks [4096,16384): cast chunk (float4 each).
// ---------------------------------------------------------------------------
__global__ __launch_bounds__(256) void ln_cast(const float* __restrict__ x,
                                               const float* __restrict__ g,
                                               const float* __restrict__ bt,
                                               __bf16* __restrict__ y,
                                               const float* __restrict__ key,
                                               const float* __restrict__ value,
                                               const float* __restrict__ wq,
                                               const float* __restrict__ wk,
                                               const float* __restrict__ wv,
                                               const float* __restrict__ wo,
                                               __bf16* kb, __bf16* vb, __bf16* wqb,
                                               __bf16* wkb, __bf16* wvb, __bf16* wob) {
    int tid = threadIdx.x;
    if (blockIdx.x < 4096) {
        int row = blockIdx.x;
        __shared__ float red[2][4];
        float4 v = ((const float4*)(x + (size_t)row * DMODEL))[tid];
        float s  = v.x + v.y + v.z + v.w;
        float sq = v.x * v.x + v.y * v.y + v.z * v.z + v.w * v.w;
        #pragma unroll
        for (int o = 32; o; o >>= 1) { s += __shfl_xor(s, o, 64); sq += __shfl_xor(sq, o, 64); }
        int wv_ = tid >> 6;
        if ((tid & 63) == 0) { red[0][wv_] = s; red[1][wv_] = sq; }
        __syncthreads();
        s  = red[0][0] + red[0][1] + red[0][2] + red[0][3];
        sq = red[1][0] + red[1][1] + red[1][2] + red[1][3];
        float mu  = s * (1.0f / DMODEL);
        float var = sq * (1.0f / DMODEL) - mu * mu;
        float rs  = rsqrtf(var + 1e-6f);
        float4 gg = ((const float4*)g)[tid];
        float4 bb = ((const float4*)bt)[tid];
        bf16x4 o;
        o[0] = (__bf16)((v.x - mu) * rs * gg.x + bb.x);
        o[1] = (__bf16)((v.y - mu) * rs * gg.y + bb.y);
        o[2] = (__bf16)((v.z - mu) * rs * gg.z + bb.z);
        o[3] = (__bf16)((v.w - mu) * rs * gg.w + bb.w);
        *(bf16x4*)&y[(size_t)row * DMODEL + tid * 4] = o;
    } else {
        int i = (blockIdx.x - 4096) * 256 + tid;    // float4 index, [0, 3145728)
        const float* src; __bf16* dst; int off;
        if (i < 1048576)      { src = key;   dst = kb;  off = i; }
        else if (i < 2097152) { src = value; dst = vb;  off = i - 1048576; }
        else if (i < 2359296) { src = wq;    dst = wqb; off = i - 2097152; }
        else if (i < 2621440) { src = wk;    dst = wkb; off = i - 2359296; }
        else if (i < 2883584) { src = wv;    dst = wvb; off = i - 2621440; }
        else                  { src = wo;    dst = wob; off = i - 2883584; }
        float4 v = ((const float4*)src)[off];
        bf16x4 o = {(__bf16)v.x, (__bf16)v.y, (__bf16)v.z, (__bf16)v.w};
        *(bf16x4*)&dst[(size_t)off * 4] = o;
    }
}

// ---------------------------------------------------------------------------
// Fused Q/K/V projections, 128x64 tiles -> 3 x 512 = 1536 blocks (6/CU).
// mode 0: Q -> bf16 [b,h,s,64] scaled (1/8)*log2(e) [exp2-domain softmax];
// mode 1: K; mode 2: V transposed.
// ---------------------------------------------------------------------------
__global__ __launch_bounds__(256) void qkv_proj(const __bf16* __restrict__ qn,
                                                const __bf16* __restrict__ kb,
                                                const __bf16* __restrict__ vb,
                                                const __bf16* __restrict__ wqb,
                                                const __bf16* __restrict__ wkb,
                                                const __bf16* __restrict__ wvb,
                                                __bf16* __restrict__ Qp,
                                                __bf16* __restrict__ Kp,
                                                __bf16* __restrict__ Vt) {
    const int Kd = 1024;
    __shared__ __bf16 As[128][32];
    __shared__ __bf16 Bs[64][32];
    int mode = blockIdx.x >> 9;               // 0,1,2
    int t = blockIdx.x & 511;
    int tm = t >> 4, tn = t & 15;             // 32 x 16 tiles (M=4096, N=1024)
    int tid = threadIdx.x, lane = tid & 63, wv = tid >> 6;
    int wr = (wv >> 1) * 64, wc = (wv & 1) * 32;
    int lr = lane & 15, lg = lane >> 4;
    int r0 = tid >> 2, c0 = (tid & 3) * 8;

    const __bf16* A = (mode == 0) ? qn : (mode == 1) ? kb : vb;
    const __bf16* W = (mode == 0) ? wqb : (mode == 1) ? wkb : wvb;

    f32x4 acc[4][2] = {};
    const __bf16* Arow = A + (size_t)(tm * 128) * Kd;
    const __bf16* Brow = W + (size_t)(tn * 64) * Kd;

    for (int kt = 0; kt < Kd; kt += 32) {
        __syncthreads();
        gload_lds16(&Arow[(size_t)r0 * Kd + kt + c0],        &As[r0][c0]);
        gload_lds16(&Arow[(size_t)(r0 + 64) * Kd + kt + c0], &As[r0 + 64][c0]);
        gload_lds16(&Brow[(size_t)r0 * Kd + kt + c0],        &Bs[r0][c0]);
        __syncthreads();
        bf16x8 af[4], bg[2];
        #pragma unroll
        for (int m = 0; m < 4; ++m) af[m] = *(bf16x8*)&As[wr + m * 16 + lr][lg * 8];
        #pragma unroll
        for (int n = 0; n < 2; ++n) bg[n] = *(bf16x8*)&Bs[wc + n * 16 + lr][lg * 8];
        #pragma unroll
        for (int m = 0; m < 4; ++m)
            #pragma unroll
            for (int n = 0; n < 2; ++n)
                acc[m][n] = __builtin_amdgcn_mfma_f32_16x16x32_bf16(af[m], bg[n], acc[m][n], 0, 0, 0);
    }

    if (mode < 2) {
        float scale = (mode == 0) ? (0.125f * LOG2E) : 1.0f;
        __bf16* C = (mode == 0) ? Qp : Kp;
        #pragma unroll
        for (int m = 0; m < 4; ++m)
            #pragma unroll
            for (int n = 0; n < 2; ++n)
                #pragma unroll
                for (int r = 0; r < 4; ++r) {
                    int grow = tm * 128 + wr + m * 16 + lg * 4 + r;
                    int gcol = tn * 64 + wc + n * 16 + lr;
                    int b = grow >> 11, ss = grow & 2047, h = gcol >> 6, d = gcol & 63;
                    C[((size_t)(b * NUM_HEAD + h) * SEQ + ss) * DK + d] = (__bf16)(acc[m][n][r] * scale);
                }
    } else {
        #pragma unroll
        for (int m = 0; m < 4; ++m)
            #pragma unroll
            for (int n = 0; n < 2; ++n)
                #pragma unroll
                for (int r = 0; r < 4; ++r) {
                    int grow = tm * 128 + wr + m * 16 + lg * 4 + r;
                    int gcol = tn * 64 + wc + n * 16 + lr;
                    int b = grow >> 11, ss = grow & 2047, h = gcol >> 6, d = gcol & 63;
                    Vt[((size_t)(b * NUM_HEAD + h) * DK + d) * SEQ + ss] = (__bf16)acc[m][n][r];
                }
    }
}

// ---------------------------------------------------------------------------
// Output projection + residual, 128x64 tiles -> 512 blocks (2/CU).
// nt store: out is write-once, keep L2 for operands.
// ---------------------------------------------------------------------------
__global__ __launch_bounds__(256) void out_gemm(const __bf16* __restrict__ A,
                                                const __bf16* __restrict__ Bw,
                                                const float* __restrict__ residual,
                                                float* __restrict__ out) {
    const int Kd = 1024;
    __shared__ __bf16 As[128][32];
    __shared__ __bf16 Bs[64][32];
    int tm = blockIdx.x >> 4, tn = blockIdx.x & 15;
    int tid = threadIdx.x, lane = tid & 63, wv = tid >> 6;
    int wr = (wv >> 1) * 64, wc = (wv & 1) * 32;
    int lr = lane & 15, lg = lane >> 4;
    int r0 = tid >> 2, c0 = (tid & 3) * 8;

    f32x4 acc[4][2] = {};
    const __bf16* Arow = A  + (size_t)(tm * 128) * Kd;
    const __bf16* Brow = Bw + (size_t)(tn * 64) * Kd;

    for (int kt = 0; kt < Kd; kt += 32) {
        __syncthreads();
        gload_lds16(&Arow[(size_t)r0 * Kd + kt + c0],        &As[r0][c0]);
        gload_lds16(&Arow[(size_t)(r0 + 64) * Kd + kt + c0], &As[r0 + 64][c0]);
        gload_lds16(&Brow[(size_t)r0 * Kd + kt + c0],        &Bs[r0][c0]);
        __syncthreads();
        bf16x8 af[4], bg[2];
        #pragma unroll
        for (int m = 0; m < 4; ++m) af[m] = *(bf16x8*)&As[wr + m * 16 + lr][lg * 8];
        #pragma unroll
        for (int n = 0; n < 2; ++n) bg[n] = *(bf16x8*)&Bs[wc + n * 16 + lr][lg * 8];
        #pragma unroll
        for (int m = 0; m < 4; ++m)
            #pragma unroll
            for (int n = 0; n < 2; ++n)
                acc[m][n] = __builtin_amdgcn_mfma_f32_16x16x32_bf16(af[m], bg[n], acc[m][n], 0, 0, 0);
    }

    #pragma unroll
    for (int m = 0; m < 4; ++m)
        #pragma unroll
        for (int n = 0; n < 2; ++n)
            #pragma unroll
            for (int r = 0; r < 4; ++r) {
                int grow = tm * 128 + wr + m * 16 + lg * 4 + r;
                int gcol = tn * 64 + wc + n * 16 + lr;
                size_t idx = (size_t)grow * DMODEL + gcol;
                __builtin_nontemporal_store(acc[m][n][r] + residual[idx], &out[idx]);
            }
}

// ---------------------------------------------------------------------------
// Attention, flash-style two-phase, swapped QK^T (32x32x16 MFMA).
// Round-8 verified structure + (1) nt P-stores (protect L2-resident K/V),
// (2) K double-buffer prefetch + V-load hoist, (3) exp2-domain softmax
// (log2e folded into Qp). Grid 2048 blocks (XCD-chunked), 4 waves.
// ---------------------------------------------------------------------------
__global__ __launch_bounds__(256) void attn_kernel(const __bf16* __restrict__ Qp,
                                                   const __bf16* __restrict__ Kp,
                                                   const __bf16* __restrict__ Vt,
                                                   float* __restrict__ attn_out,
                                                   __bf16* __restrict__ out_heads) {
    __shared__ float ored[4][32][68];
    __shared__ float mlred[4][32][2];

    int bid = blockIdx.x;
    int wid = (bid & 7) * 256 + (bid >> 3);   // XCD-chunked: each XCD gets 4 heads
    int bh = wid >> 6;
    int qbase = (wid & 63) * 32;
    int tid = threadIdx.x, lane = tid & 63, wv = tid >> 6;
    int l31 = lane & 31, hi = lane >> 5;

    const __bf16* Qh = Qp + ((size_t)bh * SEQ + qbase) * DK;
    const __bf16* Kh = Kp + (size_t)bh * SEQ * DK;
    const __bf16* Vh = Vt + (size_t)bh * DK * SEQ;

    bf16x8 qf[4];
    #pragma unroll
    for (int s = 0; s < 4; ++s)
        qf[s] = *(const bf16x8*)&Qh[(size_t)l31 * DK + s * 16 + hi * 8];

    int kbase = wv * 512;

    auto loadK = [&](bf16x8 (&kf)[4], int k0) {
        #pragma unroll
        for (int s = 0; s < 4; ++s)
            kf[s] = *(const bf16x8*)&Kh[(size_t)(k0 + l31) * DK + s * 16 + hi * 8];
    };

    // ---- Phase A: online max / sum (log2 domain) over this wave's 512 keys ----
    float m = -1e30f, lsum = 0.f;
    auto tileA = [&](const bf16x8 (&kf)[4]) {
        f32x16 dd;
        #pragma unroll
        for (int r = 0; r < 16; ++r) dd[r] = 0.f;
        __builtin_amdgcn_s_setprio(1);
        #pragma unroll
        for (int s = 0; s < 4; ++s)
            dd = __builtin_amdgcn_mfma_f32_32x32x16_bf16(kf[s], qf[s], dd, 0, 0, 0);
        __builtin_amdgcn_s_setprio(0);
        float m8[8];
        #pragma unroll
        for (int r = 0; r < 8; ++r) m8[r] = fmaxf(dd[r], dd[r + 8]);
        #pragma unroll
        for (int r = 0; r < 4; ++r) m8[r] = fmaxf(m8[r], m8[r + 4]);
        float pmax = fmaxf(fmaxf(m8[0], m8[1]), fmaxf(m8[2], m8[3]));
        if (!__all(pmax - m <= 11.0f)) {   // defer-max (log2 domain)
            float nm = fmaxf(m, pmax);
            lsum *= exp2f(m - nm);
            m = nm;
        }
        float es[4] = {0.f, 0.f, 0.f, 0.f};
        #pragma unroll
        for (int r = 0; r < 16; ++r) es[r & 3] += exp2f(dd[r] - m);
        lsum += (es[0] + es[1]) + (es[2] + es[3]);
    };
    {
        bf16x8 kA[4], kB[4];
        loadK(kA, kbase);
        for (int t = 0; t < 16; t += 2) {
            loadK(kB, kbase + (t + 1) * 32);
            tileA(kA);
            if (t + 2 < 16) loadK(kA, kbase + (t + 2) * 32);
            tileA(kB);
        }
    }
    {   // merge interleaved key-halves (lane ^ 32, same q)
        float mo = __shfl_xor(m, 32, 64);
        float lo_ = __shfl_xor(lsum, 32, 64);
        float nm = fmaxf(m, mo);
        lsum = lsum * exp2f(m - nm) + lo_ * exp2f(mo - nm);
        m = nm;
    }
    if (hi == 0) { mlred[wv][l31][0] = m; mlred[wv][l31][1] = lsum; }
    __syncthreads();
    {   // merge across 4 waves (disjoint key ranges)
        float fm = -1e30f;
        #pragma unroll
        for (int w = 0; w < 4; ++w) fm = fmaxf(fm, mlred[w][l31][0]);
        float fl = 0.f;
        #pragma unroll
        for (int w = 0; w < 4; ++w) fl += mlred[w][l31][1] * exp2f(mlred[w][l31][0] - fm);
        m = fm;
        lsum = fl;
    }
    float invl = 1.0f / lsum;

    // ---- Phase B: normalized P, nt global write, PV ----
    float* attn_base = attn_out + ((size_t)bh * SEQ + qbase) * SEQ;
    f32x16 o0, o1;
    #pragma unroll
    for (int r = 0; r < 16; ++r) { o0[r] = 0.f; o1[r] = 0.f; }

    auto tileB = [&](const bf16x8 (&kf)[4], int k0) {
        f32x16 dd;
        #pragma unroll
        for (int r = 0; r < 16; ++r) dd[r] = 0.f;
        __builtin_amdgcn_s_setprio(1);
        #pragma unroll
        for (int s = 0; s < 4; ++s)
            dd = __builtin_amdgcn_mfma_f32_32x32x16_bf16(kf[s], qf[s], dd, 0, 0, 0);
        __builtin_amdgcn_s_setprio(0);

        // hoist V loads (hide L2 latency under exp/pack)
        bf16x8 vf00 = *(const bf16x8*)&Vh[(size_t)(l31)      * SEQ + k0 + hi * 8];
        bf16x8 vf01 = *(const bf16x8*)&Vh[(size_t)(32 + l31) * SEQ + k0 + hi * 8];
        bf16x8 vf10 = *(const bf16x8*)&Vh[(size_t)(l31)      * SEQ + k0 + 16 + hi * 8];
        bf16x8 vf11 = *(const bf16x8*)&Vh[(size_t)(32 + l31) * SEQ + k0 + 16 + hi * 8];

        float p[16];
        #pragma unroll
        for (int r = 0; r < 16; ++r) p[r] = exp2f(dd[r] - m) * invl;

        // direct nt P write: reg quad q4 = keys k0 + 8*q4 + 4*hi + (0..3), row q=l31
        #pragma unroll
        for (int q4 = 0; q4 < 4; ++q4) {
            f32x4 v4 = {p[4 * q4], p[4 * q4 + 1], p[4 * q4 + 2], p[4 * q4 + 3]};
            __builtin_nontemporal_store(v4,
                (f32x4*)&attn_base[(size_t)l31 * SEQ + k0 + 8 * q4 + 4 * hi]);
        }

        // pack P to bf16 pair-words: w[i] = keys(reg 2i, 2i+1)
        unsigned int w[8];
        #pragma unroll
        for (int i = 0; i < 8; ++i) {
            union { __bf16 h[2]; unsigned int u; } bw;
            bw.h[0] = (__bf16)p[2 * i];
            bw.h[1] = (__bf16)p[2 * i + 1];
            w[i] = bw.u;
        }
        __builtin_amdgcn_s_setprio(1);
        {   // slot 0 (keys k0..k0+15)
            unsigned int s0 = (unsigned int)__shfl_xor((int)w[0], 32, 64);
            unsigned int s1 = (unsigned int)__shfl_xor((int)w[1], 32, 64);
            unsigned int s2 = (unsigned int)__shfl_xor((int)w[2], 32, 64);
            unsigned int s3 = (unsigned int)__shfl_xor((int)w[3], 32, 64);
            union { unsigned int u[4]; bf16x8 v; } pa;
            pa.u[0] = hi ? s2 : w[0];
            pa.u[1] = hi ? s3 : w[1];
            pa.u[2] = hi ? w[2] : s0;
            pa.u[3] = hi ? w[3] : s1;
            o0 = __builtin_amdgcn_mfma_f32_32x32x16_bf16(pa.v, vf00, o0, 0, 0, 0);
            o1 = __builtin_amdgcn_mfma_f32_32x32x16_bf16(pa.v, vf01, o1, 0, 0, 0);
        }
        {   // slot 1 (keys k0+16..k0+31)
            unsigned int s0 = (unsigned int)__shfl_xor((int)w[4], 32, 64);
            unsigned int s1 = (unsigned int)__shfl_xor((int)w[5], 32, 64);
            unsigned int s2 = (unsigned int)__shfl_xor((int)w[6], 32, 64);
            unsigned int s3 = (unsigned int)__shfl_xor((int)w[7], 32, 64);
            union { unsigned int u[4]; bf16x8 v; } pa;
            pa.u[0] = hi ? s2 : w[4];
            pa.u[1] = hi ? s3 : w[5];
            pa.u[2] = hi ? w[6] : s0;
            pa.u[3] = hi ? w[7] : s1;
            o0 = __builtin_amdgcn_mfma_f32_32x32x16_bf16(pa.v, vf10, o0, 0, 0, 0);
            o1 = __builtin_amdgcn_mfma_f32_32x32x16_bf16(pa.v, vf11, o1, 0, 0, 0);
        }
        __builtin_amdgcn_s_setprio(0);
    };
    {
        bf16x8 kA[4], kB[4];
        loadK(kA, kbase);
        for (int t = 0; t < 16; t += 2) {
            loadK(kB, kbase + (t + 1) * 32);
            tileB(kA, kbase + t * 32);
            if (t + 2 < 16) loadK(kA, kbase + (t + 2) * 32);
            tileB(kB, kbase + (t + 1) * 32);
        }
    }

    // ---- cross-wave O reduce, write out_heads ----
    #pragma unroll
    for (int r = 0; r < 16; ++r) {
        int q = (r & 3) + 8 * (r >> 2) + 4 * hi;
        ored[wv][q][l31]      = o0[r];
        ored[wv][q][32 + l31] = o1[r];
    }
    __syncthreads();
    {
        int q = tid >> 3, d0 = (tid & 7) * 8;
        float s[8];
        #pragma unroll
        for (int j = 0; j < 8; ++j) s[j] = 0.f;
        #pragma unroll
        for (int w = 0; w < 4; ++w)
            #pragma unroll
            for (int j = 0; j < 8; ++j) s[j] += ored[w][q][d0 + j];
        int b = bh >> 4, h = bh & 15;
        bf16x8 ov;
        #pragma unroll
        for (int j = 0; j < 8; ++j) ov[j] = (__bf16)s[j];
        *(bf16x8*)&out_heads[((size_t)(b * SEQ + qbase + q)) * DMODEL + h * DK + d0] = ov;
    }
}

// ---------------------------------------------------------------------------
extern "C" void kernel_launch(void* const* d_in, const int* in_sizes, int n_in,
                              void* d_out, int out_size, void* d_ws, size_t ws_size,
                              hipStream_t stream) {
    const float* query = (const float*)d_in[0];
    const float* key   = (const float*)d_in[1];
    const float* value = (const float*)d_in[2];
    const float* w_q   = (const float*)d_in[3];
    const float* w_k   = (const float*)d_in[4];
    const float* w_v   = (const float*)d_in[5];
    const float* w_o   = (const float*)d_in[6];
    const float* lng   = (const float*)d_in[7];
    const float* lnb   = (const float*)d_in[8];

    char* ws = (char*)d_ws;
    __bf16* qn  = (__bf16*)(ws);                    // 8 MB  LN(query) bf16
    __bf16* kb  = (__bf16*)(ws + ( 8u << 20));      // 8 MB  key bf16
    __bf16* vb  = (__bf16*)(ws + (16u << 20));      // 8 MB  value bf16
    __bf16* wqb = (__bf16*)(ws + (24u << 20));      // 2 MB
    __bf16* wkb = (__bf16*)(ws + (26u << 20));      // 2 MB
    __bf16* wvb = (__bf16*)(ws + (28u << 20));      // 2 MB
    __bf16* wob = (__bf16*)(ws + (30u << 20));      // 2 MB
    __bf16* Qp  = (__bf16*)(ws + (32u << 20));      // 8 MB  [b,h,s,64] (x(1/8)*log2e)
    __bf16* Kp  = (__bf16*)(ws + (40u << 20));      // 8 MB  [b,h,s,64]
    __bf16* Vt  = (__bf16*)(ws + (48u << 20));      // 8 MB  [b,h,64,s']
    __bf16* oh  = (__bf16*)(ws + (56u << 20));      // 8 MB  attention out [4096,1024]

    float* out  = (float*)d_out;
    float* attn = out + (size_t)MROWS * DMODEL;

    ln_cast<<<16384, 256, 0, stream>>>(query, lng, lnb, qn,
                                       key, value, w_q, w_k, w_v, w_o,
                                       kb, vb, wqb, wkb, wvb, wob);

    qkv_proj<<<1536, 256, 0, stream>>>(qn, kb, vb, wqb, wkb, wvb, Qp, Kp, Vt);

    attn_kernel<<<2048, 256, 0, stream>>>(Qp, Kp, Vt, attn, oh);

    out_gemm<<<512, 256, 0, stream>>>(oh, wob, query, out);
}

// Round 10
// 353.565 us; speedup vs baseline: 1.1685x; 1.1685x over previous
//
#include <hip/hip_runtime.h>
#include <hip/hip_bf16.h>

// ---------------------------------------------------------------------------
// MultiheadAttention fused pipeline for MI355X (gfx950)
// B=2, S=S'=2048, H=16, D_MODEL=1024, dk=dv=64
// outputs: out [2,2048,1024] fp32, attn [2,16,2048,2048] fp32 (concat in d_out)
// ---------------------------------------------------------------------------

typedef __bf16 bf16x8 __attribute__((ext_vector_type(8)));
typedef __bf16 bf16x4 __attribute__((ext_vector_type(4)));
typedef float  f32x4  __attribute__((ext_vector_type(4)));
typedef float  f32x16 __attribute__((ext_vector_type(16)));

#define NUM_HEAD 16
#define SEQ 2048
#define DMODEL 1024
#define DK 64
#define MROWS 4096      // B*S
#define LOG2E 1.44269504088896340736f

__device__ __forceinline__ void gload_lds16(const void* g, void* l) {
    __builtin_amdgcn_global_load_lds((const __attribute__((address_space(1))) void*)g,
                                     (__attribute__((address_space(3))) void*)l, 16, 0, 0);
}

// ---------------------------------------------------------------------------
// Fused LayerNorm(query)->bf16  +  all fp32->bf16 casts, one dispatch.
// blocks [0,4096): LN row; blocks [4096,16384): cast chunk (float4 each).
// ---------------------------------------------------------------------------
__global__ __launch_bounds__(256) void ln_cast(const float* __restrict__ x,
                                               const float* __restrict__ g,
                                               const float* __restrict__ bt,
                                               __bf16* __restrict__ y,
                                               const float* __restrict__ key,
                                               const float* __restrict__ value,
                                               const float* __restrict__ wq,
                                               const float* __restrict__ wk,
                                               const float* __restrict__ wv,
                                               const float* __restrict__ wo,
                                               __bf16* kb, __bf16* vb, __bf16* wqb,
                                               __bf16* wkb, __bf16* wvb, __bf16* wob) {
    int tid = threadIdx.x;
    if (blockIdx.x < 4096) {
        int row = blockIdx.x;
        __shared__ float red[2][4];
        float4 v = ((const float4*)(x + (size_t)row * DMODEL))[tid];
        float s  = v.x + v.y + v.z + v.w;
        float sq = v.x * v.x + v.y * v.y + v.z * v.z + v.w * v.w;
        #pragma unroll
        for (int o = 32; o; o >>= 1) { s += __shfl_xor(s, o, 64); sq += __shfl_xor(sq, o, 64); }
        int wv_ = tid >> 6;
        if ((tid & 63) == 0) { red[0][wv_] = s; red[1][wv_] = sq; }
        __syncthreads();
        s  = red[0][0] + red[0][1] + red[0][2] + red[0][3];
        sq = red[1][0] + red[1][1] + red[1][2] + red[1][3];
        float mu  = s * (1.0f / DMODEL);
        float var = sq * (1.0f / DMODEL) - mu * mu;
        float rs  = rsqrtf(var + 1e-6f);
        float4 gg = ((const float4*)g)[tid];
        float4 bb = ((const float4*)bt)[tid];
        bf16x4 o;
        o[0] = (__bf16)((v.x - mu) * rs * gg.x + bb.x);
        o[1] = (__bf16)((v.y - mu) * rs * gg.y + bb.y);
        o[2] = (__bf16)((v.z - mu) * rs * gg.z + bb.z);
        o[3] = (__bf16)((v.w - mu) * rs * gg.w + bb.w);
        *(bf16x4*)&y[(size_t)row * DMODEL + tid * 4] = o;
    } else {
        int i = (blockIdx.x - 4096) * 256 + tid;    // float4 index, [0, 3145728)
        const float* src; __bf16* dst; int off;
        if (i < 1048576)      { src = key;   dst = kb;  off = i; }
        else if (i < 2097152) { src = value; dst = vb;  off = i - 1048576; }
        else if (i < 2359296) { src = wq;    dst = wqb; off = i - 2097152; }
        else if (i < 2621440) { src = wk;    dst = wkb; off = i - 2359296; }
        else if (i < 2883584) { src = wv;    dst = wvb; off = i - 2621440; }
        else                  { src = wo;    dst = wob; off = i - 2883584; }
        float4 v = ((const float4*)src)[off];
        bf16x4 o = {(__bf16)v.x, (__bf16)v.y, (__bf16)v.z, (__bf16)v.w};
        *(bf16x4*)&dst[(size_t)off * 4] = o;
    }
}

// ---------------------------------------------------------------------------
// Fused Q/K/V projections, 128x64 tiles -> 3 x 512 = 1536 blocks (6/CU).
// mode 0: Q -> bf16 [b,h,s,64] scaled (1/8)*log2(e) [exp2-domain softmax];
// mode 1: K; mode 2: V transposed.
// ---------------------------------------------------------------------------
__global__ __launch_bounds__(256) void qkv_proj(const __bf16* __restrict__ qn,
                                                const __bf16* __restrict__ kb,
                                                const __bf16* __restrict__ vb,
                                                const __bf16* __restrict__ wqb,
                                                const __bf16* __restrict__ wkb,
                                                const __bf16* __restrict__ wvb,
                                                __bf16* __restrict__ Qp,
                                                __bf16* __restrict__ Kp,
                                                __bf16* __restrict__ Vt) {
    const int Kd = 1024;
    __shared__ __bf16 As[128][32];
    __shared__ __bf16 Bs[64][32];
    int mode = blockIdx.x >> 9;               // 0,1,2
    int t = blockIdx.x & 511;
    int tm = t >> 4, tn = t & 15;             // 32 x 16 tiles (M=4096, N=1024)
    int tid = threadIdx.x, lane = tid & 63, wv = tid >> 6;
    int wr = (wv >> 1) * 64, wc = (wv & 1) * 32;
    int lr = lane & 15, lg = lane >> 4;
    int r0 = tid >> 2, c0 = (tid & 3) * 8;

    const __bf16* A = (mode == 0) ? qn : (mode == 1) ? kb : vb;
    const __bf16* W = (mode == 0) ? wqb : (mode == 1) ? wkb : wvb;

    f32x4 acc[4][2] = {};
    const __bf16* Arow = A + (size_t)(tm * 128) * Kd;
    const __bf16* Brow = W + (size_t)(tn * 64) * Kd;

    for (int kt = 0; kt < Kd; kt += 32) {
        __syncthreads();
        gload_lds16(&Arow[(size_t)r0 * Kd + kt + c0],        &As[r0][c0]);
        gload_lds16(&Arow[(size_t)(r0 + 64) * Kd + kt + c0], &As[r0 + 64][c0]);
        gload_lds16(&Brow[(size_t)r0 * Kd + kt + c0],        &Bs[r0][c0]);
        __syncthreads();
        bf16x8 af[4], bg[2];
        #pragma unroll
        for (int m = 0; m < 4; ++m) af[m] = *(bf16x8*)&As[wr + m * 16 + lr][lg * 8];
        #pragma unroll
        for (int n = 0; n < 2; ++n) bg[n] = *(bf16x8*)&Bs[wc + n * 16 + lr][lg * 8];
        #pragma unroll
        for (int m = 0; m < 4; ++m)
            #pragma unroll
            for (int n = 0; n < 2; ++n)
                acc[m][n] = __builtin_amdgcn_mfma_f32_16x16x32_bf16(af[m], bg[n], acc[m][n], 0, 0, 0);
    }

    if (mode < 2) {
        float scale = (mode == 0) ? (0.125f * LOG2E) : 1.0f;
        __bf16* C = (mode == 0) ? Qp : Kp;
        #pragma unroll
        for (int m = 0; m < 4; ++m)
            #pragma unroll
            for (int n = 0; n < 2; ++n)
                #pragma unroll
                for (int r = 0; r < 4; ++r) {
                    int grow = tm * 128 + wr + m * 16 + lg * 4 + r;
                    int gcol = tn * 64 + wc + n * 16 + lr;
                    int b = grow >> 11, ss = grow & 2047, h = gcol >> 6, d = gcol & 63;
                    C[((size_t)(b * NUM_HEAD + h) * SEQ + ss) * DK + d] = (__bf16)(acc[m][n][r] * scale);
                }
    } else {
        #pragma unroll
        for (int m = 0; m < 4; ++m)
            #pragma unroll
            for (int n = 0; n < 2; ++n)
                #pragma unroll
                for (int r = 0; r < 4; ++r) {
                    int grow = tm * 128 + wr + m * 16 + lg * 4 + r;
                    int gcol = tn * 64 + wc + n * 16 + lr;
                    int b = grow >> 11, ss = grow & 2047, h = gcol >> 6, d = gcol & 63;
                    Vt[((size_t)(b * NUM_HEAD + h) * DK + d) * SEQ + ss] = (__bf16)acc[m][n][r];
                }
    }
}

// ---------------------------------------------------------------------------
// Output projection + residual, 128x64 tiles -> 512 blocks (2/CU).
// ---------------------------------------------------------------------------
__global__ __launch_bounds__(256) void out_gemm(const __bf16* __restrict__ A,
                                                const __bf16* __restrict__ Bw,
                                                const float* __restrict__ residual,
                                                float* __restrict__ out) {
    const int Kd = 1024;
    __shared__ __bf16 As[128][32];
    __shared__ __bf16 Bs[64][32];
    int tm = blockIdx.x >> 4, tn = blockIdx.x & 15;
    int tid = threadIdx.x, lane = tid & 63, wv = tid >> 6;
    int wr = (wv >> 1) * 64, wc = (wv & 1) * 32;
    int lr = lane & 15, lg = lane >> 4;
    int r0 = tid >> 2, c0 = (tid & 3) * 8;

    f32x4 acc[4][2] = {};
    const __bf16* Arow = A  + (size_t)(tm * 128) * Kd;
    const __bf16* Brow = Bw + (size_t)(tn * 64) * Kd;

    for (int kt = 0; kt < Kd; kt += 32) {
        __syncthreads();
        gload_lds16(&Arow[(size_t)r0 * Kd + kt + c0],        &As[r0][c0]);
        gload_lds16(&Arow[(size_t)(r0 + 64) * Kd + kt + c0], &As[r0 + 64][c0]);
        gload_lds16(&Brow[(size_t)r0 * Kd + kt + c0],        &Bs[r0][c0]);
        __syncthreads();
        bf16x8 af[4], bg[2];
        #pragma unroll
        for (int m = 0; m < 4; ++m) af[m] = *(bf16x8*)&As[wr + m * 16 + lr][lg * 8];
        #pragma unroll
        for (int n = 0; n < 2; ++n) bg[n] = *(bf16x8*)&Bs[wc + n * 16 + lr][lg * 8];
        #pragma unroll
        for (int m = 0; m < 4; ++m)
            #pragma unroll
            for (int n = 0; n < 2; ++n)
                acc[m][n] = __builtin_amdgcn_mfma_f32_16x16x32_bf16(af[m], bg[n], acc[m][n], 0, 0, 0);
    }

    #pragma unroll
    for (int m = 0; m < 4; ++m)
        #pragma unroll
        for (int n = 0; n < 2; ++n)
            #pragma unroll
            for (int r = 0; r < 4; ++r) {
                int grow = tm * 128 + wr + m * 16 + lg * 4 + r;
                int gcol = tn * 64 + wc + n * 16 + lr;
                size_t idx = (size_t)grow * DMODEL + gcol;
                out[idx] = acc[m][n][r] + residual[idx];
            }
}

// ---------------------------------------------------------------------------
// Attention, flash-style two-phase, swapped QK^T (32x32x16 MFMA).
// Round-8 verified structure + exp2-domain softmax + K dbuf prefetch +
// V-load hoist + setprio.  P stores are NORMAL (L2 write-combining; r9's nt
// caused 1.6x write amplification).  O-reduce buffer in bf16: LDS 35.8->19.5KB
// -> 5 blocks/CU residency (VGPR-limited), up from 4 (LDS-limited).
// ---------------------------------------------------------------------------
__global__ __launch_bounds__(256) void attn_kernel(const __bf16* __restrict__ Qp,
                                                   const __bf16* __restrict__ Kp,
                                                   const __bf16* __restrict__ Vt,
                                                   float* __restrict__ attn_out,
                                                   __bf16* __restrict__ out_heads) {
    __shared__ __bf16 ored[4][32][72];   // 18,432 B (bf16 partials)
    __shared__ float  mlred[4][32][2];   //  1,024 B

    int bid = blockIdx.x;
    int wid = (bid & 7) * 256 + (bid >> 3);   // XCD-chunked: each XCD gets 4 heads
    int bh = wid >> 6;
    int qbase = (wid & 63) * 32;
    int tid = threadIdx.x, lane = tid & 63, wv = tid >> 6;
    int l31 = lane & 31, hi = lane >> 5;

    const __bf16* Qh = Qp + ((size_t)bh * SEQ + qbase) * DK;
    const __bf16* Kh = Kp + (size_t)bh * SEQ * DK;
    const __bf16* Vh = Vt + (size_t)bh * DK * SEQ;

    bf16x8 qf[4];
    #pragma unroll
    for (int s = 0; s < 4; ++s)
        qf[s] = *(const bf16x8*)&Qh[(size_t)l31 * DK + s * 16 + hi * 8];

    int kbase = wv * 512;

    auto loadK = [&](bf16x8 (&kf)[4], int k0) {
        #pragma unroll
        for (int s = 0; s < 4; ++s)
            kf[s] = *(const bf16x8*)&Kh[(size_t)(k0 + l31) * DK + s * 16 + hi * 8];
    };

    // ---- Phase A: online max / sum (log2 domain) over this wave's 512 keys ----
    float m = -1e30f, lsum = 0.f;
    auto tileA = [&](const bf16x8 (&kf)[4]) {
        f32x16 dd;
        #pragma unroll
        for (int r = 0; r < 16; ++r) dd[r] = 0.f;
        __builtin_amdgcn_s_setprio(1);
        #pragma unroll
        for (int s = 0; s < 4; ++s)
            dd = __builtin_amdgcn_mfma_f32_32x32x16_bf16(kf[s], qf[s], dd, 0, 0, 0);
        __builtin_amdgcn_s_setprio(0);
        float m8[8];
        #pragma unroll
        for (int r = 0; r < 8; ++r) m8[r] = fmaxf(dd[r], dd[r + 8]);
        #pragma unroll
        for (int r = 0; r < 4; ++r) m8[r] = fmaxf(m8[r], m8[r + 4]);
        float pmax = fmaxf(fmaxf(m8[0], m8[1]), fmaxf(m8[2], m8[3]));
        if (!__all(pmax - m <= 11.0f)) {   // defer-max (log2 domain)
            float nm = fmaxf(m, pmax);
            lsum *= exp2f(m - nm);
            m = nm;
        }
        float es[4] = {0.f, 0.f, 0.f, 0.f};
        #pragma unroll
        for (int r = 0; r < 16; ++r) es[r & 3] += exp2f(dd[r] - m);
        lsum += (es[0] + es[1]) + (es[2] + es[3]);
    };
    {
        bf16x8 kA[4], kB[4];
        loadK(kA, kbase);
        for (int t = 0; t < 16; t += 2) {
            loadK(kB, kbase + (t + 1) * 32);
            tileA(kA);
            if (t + 2 < 16) loadK(kA, kbase + (t + 2) * 32);
            tileA(kB);
        }
    }
    {   // merge interleaved key-halves (lane ^ 32, same q)
        float mo = __shfl_xor(m, 32, 64);
        float lo_ = __shfl_xor(lsum, 32, 64);
        float nm = fmaxf(m, mo);
        lsum = lsum * exp2f(m - nm) + lo_ * exp2f(mo - nm);
        m = nm;
    }
    if (hi == 0) { mlred[wv][l31][0] = m; mlred[wv][l31][1] = lsum; }
    __syncthreads();
    {   // merge across 4 waves (disjoint key ranges)
        float fm = -1e30f;
        #pragma unroll
        for (int w = 0; w < 4; ++w) fm = fmaxf(fm, mlred[w][l31][0]);
        float fl = 0.f;
        #pragma unroll
        for (int w = 0; w < 4; ++w) fl += mlred[w][l31][1] * exp2f(mlred[w][l31][0] - fm);
        m = fm;
        lsum = fl;
    }
    float invl = 1.0f / lsum;

    // ---- Phase B: normalized P, direct global write, PV ----
    float* attn_base = attn_out + ((size_t)bh * SEQ + qbase) * SEQ;
    f32x16 o0, o1;
    #pragma unroll
    for (int r = 0; r < 16; ++r) { o0[r] = 0.f; o1[r] = 0.f; }

    auto tileB = [&](const bf16x8 (&kf)[4], int k0) {
        f32x16 dd;
        #pragma unroll
        for (int r = 0; r < 16; ++r) dd[r] = 0.f;
        __builtin_amdgcn_s_setprio(1);
        #pragma unroll
        for (int s = 0; s < 4; ++s)
            dd = __builtin_amdgcn_mfma_f32_32x32x16_bf16(kf[s], qf[s], dd, 0, 0, 0);
        __builtin_amdgcn_s_setprio(0);

        // hoist V loads (hide L2 latency under exp/pack)
        bf16x8 vf00 = *(const bf16x8*)&Vh[(size_t)(l31)      * SEQ + k0 + hi * 8];
        bf16x8 vf01 = *(const bf16x8*)&Vh[(size_t)(32 + l31) * SEQ + k0 + hi * 8];
        bf16x8 vf10 = *(const bf16x8*)&Vh[(size_t)(l31)      * SEQ + k0 + 16 + hi * 8];
        bf16x8 vf11 = *(const bf16x8*)&Vh[(size_t)(32 + l31) * SEQ + k0 + 16 + hi * 8];

        float p[16];
        #pragma unroll
        for (int r = 0; r < 16; ++r) p[r] = exp2f(dd[r] - m) * invl;

        // direct P write: reg quad q4 = keys k0 + 8*q4 + 4*hi + (0..3), row q=l31
        #pragma unroll
        for (int q4 = 0; q4 < 4; ++q4) {
            f32x4 v4 = {p[4 * q4], p[4 * q4 + 1], p[4 * q4 + 2], p[4 * q4 + 3]};
            *(f32x4*)&attn_base[(size_t)l31 * SEQ + k0 + 8 * q4 + 4 * hi] = v4;
        }

        // pack P to bf16 pair-words: w[i] = keys(reg 2i, 2i+1)
        unsigned int w[8];
        #pragma unroll
        for (int i = 0; i < 8; ++i) {
            union { __bf16 h[2]; unsigned int u; } bw;
            bw.h[0] = (__bf16)p[2 * i];
            bw.h[1] = (__bf16)p[2 * i + 1];
            w[i] = bw.u;
        }
        __builtin_amdgcn_s_setprio(1);
        {   // slot 0 (keys k0..k0+15)
            unsigned int s0 = (unsigned int)__shfl_xor((int)w[0], 32, 64);
            unsigned int s1 = (unsigned int)__shfl_xor((int)w[1], 32, 64);
            unsigned int s2 = (unsigned int)__shfl_xor((int)w[2], 32, 64);
            unsigned int s3 = (unsigned int)__shfl_xor((int)w[3], 32, 64);
            union { unsigned int u[4]; bf16x8 v; } pa;
            pa.u[0] = hi ? s2 : w[0];
            pa.u[1] = hi ? s3 : w[1];
            pa.u[2] = hi ? w[2] : s0;
            pa.u[3] = hi ? w[3] : s1;
            o0 = __builtin_amdgcn_mfma_f32_32x32x16_bf16(pa.v, vf00, o0, 0, 0, 0);
            o1 = __builtin_amdgcn_mfma_f32_32x32x16_bf16(pa.v, vf01, o1, 0, 0, 0);
        }
        {   // slot 1 (keys k0+16..k0+31)
            unsigned int s0 = (unsigned int)__shfl_xor((int)w[4], 32, 64);
            unsigned int s1 = (unsigned int)__shfl_xor((int)w[5], 32, 64);
            unsigned int s2 = (unsigned int)__shfl_xor((int)w[6], 32, 64);
            unsigned int s3 = (unsigned int)__shfl_xor((int)w[7], 32, 64);
            union { unsigned int u[4]; bf16x8 v; } pa;
            pa.u[0] = hi ? s2 : w[4];
            pa.u[1] = hi ? s3 : w[5];
            pa.u[2] = hi ? w[6] : s0;
            pa.u[3] = hi ? w[7] : s1;
            o0 = __builtin_amdgcn_mfma_f32_32x32x16_bf16(pa.v, vf10, o0, 0, 0, 0);
            o1 = __builtin_amdgcn_mfma_f32_32x32x16_bf16(pa.v, vf11, o1, 0, 0, 0);
        }
        __builtin_amdgcn_s_setprio(0);
    };
    {
        bf16x8 kA[4], kB[4];
        loadK(kA, kbase);
        for (int t = 0; t < 16; t += 2) {
            loadK(kB, kbase + (t + 1) * 32);
            tileB(kA, kbase + t * 32);
            if (t + 2 < 16) loadK(kA, kbase + (t + 2) * 32);
            tileB(kB, kbase + (t + 1) * 32);
        }
    }

    // ---- cross-wave O reduce (bf16 partials), write out_heads ----
    #pragma unroll
    for (int r = 0; r < 16; ++r) {
        int q = (r & 3) + 8 * (r >> 2) + 4 * hi;
        ored[wv][q][l31]      = (__bf16)o0[r];
        ored[wv][q][32 + l31] = (__bf16)o1[r];
    }
    __syncthreads();
    {
        int q = tid >> 3, d0 = (tid & 7) * 8;
        float s[8];
        #pragma unroll
        for (int j = 0; j < 8; ++j) s[j] = 0.f;
        #pragma unroll
        for (int w = 0; w < 4; ++w) {
            bf16x8 pv = *(const bf16x8*)&ored[w][q][d0];
            #pragma unroll
            for (int j = 0; j < 8; ++j) s[j] += (float)pv[j];
        }
        int b = bh >> 4, h = bh & 15;
        bf16x8 ov;
        #pragma unroll
        for (int j = 0; j < 8; ++j) ov[j] = (__bf16)s[j];
        *(bf16x8*)&out_heads[((size_t)(b * SEQ + qbase + q)) * DMODEL + h * DK + d0] = ov;
    }
}

// ---------------------------------------------------------------------------
extern "C" void kernel_launch(void* const* d_in, const int* in_sizes, int n_in,
                              void* d_out, int out_size, void* d_ws, size_t ws_size,
                              hipStream_t stream) {
    const float* query = (const float*)d_in[0];
    const float* key   = (const float*)d_in[1];
    const float* value = (const float*)d_in[2];
    const float* w_q   = (const float*)d_in[3];
    const float* w_k   = (const float*)d_in[4];
    const float* w_v   = (const float*)d_in[5];
    const float* w_o   = (const float*)d_in[6];
    const float* lng   = (const float*)d_in[7];
    const float* lnb   = (const float*)d_in[8];

    char* ws = (char*)d_ws;
    __bf16* qn  = (__bf16*)(ws);                    // 8 MB  LN(query) bf16
    __bf16* kb  = (__bf16*)(ws + ( 8u << 20));      // 8 MB  key bf16
    __bf16* vb  = (__bf16*)(ws + (16u << 20));      // 8 MB  value bf16
    __bf16* wqb = (__bf16*)(ws + (24u << 20));      // 2 MB
    __bf16* wkb = (__bf16*)(ws + (26u << 20));      // 2 MB
    __bf16* wvb = (__bf16*)(ws + (28u << 20));      // 2 MB
    __bf16* wob = (__bf16*)(ws + (30u << 20));      // 2 MB
    __bf16* Qp  = (__bf16*)(ws + (32u << 20));      // 8 MB  [b,h,s,64] (x(1/8)*log2e)
    __bf16* Kp  = (__bf16*)(ws + (40u << 20));      // 8 MB  [b,h,s,64]
    __bf16* Vt  = (__bf16*)(ws + (48u << 20));      // 8 MB  [b,h,64,s']
    __bf16* oh  = (__bf16*)(ws + (56u << 20));      // 8 MB  attention out [4096,1024]

    float* out  = (float*)d_out;
    float* attn = out + (size_t)MROWS * DMODEL;

    ln_cast<<<16384, 256, 0, stream>>>(query, lng, lnb, qn,
                                       key, value, w_q, w_k, w_v, w_o,
                                       kb, vb, wqb, wkb, wvb, wob);

    qkv_proj<<<1536, 256, 0, stream>>>(qn, kb, vb, wqb, wkb, wvb, Qp, Kp, Vt);

    attn_kernel<<<2048, 256, 0, stream>>>(Qp, Kp, Vt, attn, oh);

    out_gemm<<<512, 256, 0, stream>>>(oh, wob, query, out);
}

// Round 11
// 352.386 us; speedup vs baseline: 1.1724x; 1.0033x over previous
//
#include <hip/hip_runtime.h>
#include <hip/hip_bf16.h>

// ---------------------------------------------------------------------------
// MultiheadAttention fused pipeline for MI355X (gfx950)
// B=2, S=S'=2048, H=16, D_MODEL=1024, dk=dv=64
// outputs: out [2,2048,1024] fp32, attn [2,16,2048,2048] fp32 (concat in d_out)
// ---------------------------------------------------------------------------

typedef __bf16 bf16x8 __attribute__((ext_vector_type(8)));
typedef __bf16 bf16x4 __attribute__((ext_vector_type(4)));
typedef float  f32x4  __attribute__((ext_vector_type(4)));
typedef float  f32x16 __attribute__((ext_vector_type(16)));

#define NUM_HEAD 16
#define SEQ 2048
#define DMODEL 1024
#define DK 64
#define MROWS 4096      // B*S
#define LOG2E 1.44269504088896340736f

__device__ __forceinline__ void gload_lds16(const void* g, void* l) {
    __builtin_amdgcn_global_load_lds((const __attribute__((address_space(1))) void*)g,
                                     (__attribute__((address_space(3))) void*)l, 16, 0, 0);
}

// ---------------------------------------------------------------------------
// Fused LayerNorm(query)->bf16  +  all fp32->bf16 casts, one dispatch.
// blocks [0,4096): LN row; blocks [4096,16384): cast chunk (float4 each).
// ---------------------------------------------------------------------------
__global__ __launch_bounds__(256) void ln_cast(const float* __restrict__ x,
                                               const float* __restrict__ g,
                                               const float* __restrict__ bt,
                                               __bf16* __restrict__ y,
                                               const float* __restrict__ key,
                                               const float* __restrict__ value,
                                               const float* __restrict__ wq,
                                               const float* __restrict__ wk,
                                               const float* __restrict__ wv,
                                               const float* __restrict__ wo,
                                               __bf16* kb, __bf16* vb, __bf16* wqb,
                                               __bf16* wkb, __bf16* wvb, __bf16* wob) {
    int tid = threadIdx.x;
    if (blockIdx.x < 4096) {
        int row = blockIdx.x;
        __shared__ float red[2][4];
        float4 v = ((const float4*)(x + (size_t)row * DMODEL))[tid];
        float s  = v.x + v.y + v.z + v.w;
        float sq = v.x * v.x + v.y * v.y + v.z * v.z + v.w * v.w;
        #pragma unroll
        for (int o = 32; o; o >>= 1) { s += __shfl_xor(s, o, 64); sq += __shfl_xor(sq, o, 64); }
        int wv_ = tid >> 6;
        if ((tid & 63) == 0) { red[0][wv_] = s; red[1][wv_] = sq; }
        __syncthreads();
        s  = red[0][0] + red[0][1] + red[0][2] + red[0][3];
        sq = red[1][0] + red[1][1] + red[1][2] + red[1][3];
        float mu  = s * (1.0f / DMODEL);
        float var = sq * (1.0f / DMODEL) - mu * mu;
        float rs  = rsqrtf(var + 1e-6f);
        float4 gg = ((const float4*)g)[tid];
        float4 bb = ((const float4*)bt)[tid];
        bf16x4 o;
        o[0] = (__bf16)((v.x - mu) * rs * gg.x + bb.x);
        o[1] = (__bf16)((v.y - mu) * rs * gg.y + bb.y);
        o[2] = (__bf16)((v.z - mu) * rs * gg.z + bb.z);
        o[3] = (__bf16)((v.w - mu) * rs * gg.w + bb.w);
        *(bf16x4*)&y[(size_t)row * DMODEL + tid * 4] = o;
    } else {
        int i = (blockIdx.x - 4096) * 256 + tid;    // float4 index, [0, 3145728)
        const float* src; __bf16* dst; int off;
        if (i < 1048576)      { src = key;   dst = kb;  off = i; }
        else if (i < 2097152) { src = value; dst = vb;  off = i - 1048576; }
        else if (i < 2359296) { src = wq;    dst = wqb; off = i - 2097152; }
        else if (i < 2621440) { src = wk;    dst = wkb; off = i - 2359296; }
        else if (i < 2883584) { src = wv;    dst = wvb; off = i - 2621440; }
        else                  { src = wo;    dst = wob; off = i - 2883584; }
        float4 v = ((const float4*)src)[off];
        bf16x4 o = {(__bf16)v.x, (__bf16)v.y, (__bf16)v.z, (__bf16)v.w};
        *(bf16x4*)&dst[(size_t)off * 4] = o;
    }
}

// ---------------------------------------------------------------------------
// Fused Q/K/V projections, 128x64 tiles -> 3 x 512 = 1536 blocks (6/CU).
// mode 0: Q -> bf16 [b,h,s,64] scaled (1/8)*log2(e) [exp2-domain softmax];
// mode 1: K; mode 2: V transposed.
// ---------------------------------------------------------------------------
__global__ __launch_bounds__(256) void qkv_proj(const __bf16* __restrict__ qn,
                                                const __bf16* __restrict__ kb,
                                                const __bf16* __restrict__ vb,
                                                const __bf16* __restrict__ wqb,
                                                const __bf16* __restrict__ wkb,
                                                const __bf16* __restrict__ wvb,
                                                __bf16* __restrict__ Qp,
                                                __bf16* __restrict__ Kp,
                                                __bf16* __restrict__ Vt) {
    const int Kd = 1024;
    __shared__ __bf16 As[128][32];
    __shared__ __bf16 Bs[64][32];
    int mode = blockIdx.x >> 9;               // 0,1,2
    int t = blockIdx.x & 511;
    int tm = t >> 4, tn = t & 15;             // 32 x 16 tiles (M=4096, N=1024)
    int tid = threadIdx.x, lane = tid & 63, wv = tid >> 6;
    int wr = (wv >> 1) * 64, wc = (wv & 1) * 32;
    int lr = lane & 15, lg = lane >> 4;
    int r0 = tid >> 2, c0 = (tid & 3) * 8;

    const __bf16* A = (mode == 0) ? qn : (mode == 1) ? kb : vb;
    const __bf16* W = (mode == 0) ? wqb : (mode == 1) ? wkb : wvb;

    f32x4 acc[4][2] = {};
    const __bf16* Arow = A + (size_t)(tm * 128) * Kd;
    const __bf16* Brow = W + (size_t)(tn * 64) * Kd;

    for (int kt = 0; kt < Kd; kt += 32) {
        __syncthreads();
        gload_lds16(&Arow[(size_t)r0 * Kd + kt + c0],        &As[r0][c0]);
        gload_lds16(&Arow[(size_t)(r0 + 64) * Kd + kt + c0], &As[r0 + 64][c0]);
        gload_lds16(&Brow[(size_t)r0 * Kd + kt + c0],        &Bs[r0][c0]);
        __syncthreads();
        bf16x8 af[4], bg[2];
        #pragma unroll
        for (int m = 0; m < 4; ++m) af[m] = *(bf16x8*)&As[wr + m * 16 + lr][lg * 8];
        #pragma unroll
        for (int n = 0; n < 2; ++n) bg[n] = *(bf16x8*)&Bs[wc + n * 16 + lr][lg * 8];
        #pragma unroll
        for (int m = 0; m < 4; ++m)
            #pragma unroll
            for (int n = 0; n < 2; ++n)
                acc[m][n] = __builtin_amdgcn_mfma_f32_16x16x32_bf16(af[m], bg[n], acc[m][n], 0, 0, 0);
    }

    if (mode < 2) {
        float scale = (mode == 0) ? (0.125f * LOG2E) : 1.0f;
        __bf16* C = (mode == 0) ? Qp : Kp;
        #pragma unroll
        for (int m = 0; m < 4; ++m)
            #pragma unroll
            for (int n = 0; n < 2; ++n)
                #pragma unroll
                for (int r = 0; r < 4; ++r) {
                    int grow = tm * 128 + wr + m * 16 + lg * 4 + r;
                    int gcol = tn * 64 + wc + n * 16 + lr;
                    int b = grow >> 11, ss = grow & 2047, h = gcol >> 6, d = gcol & 63;
                    C[((size_t)(b * NUM_HEAD + h) * SEQ + ss) * DK + d] = (__bf16)(acc[m][n][r] * scale);
                }
    } else {
        #pragma unroll
        for (int m = 0; m < 4; ++m)
            #pragma unroll
            for (int n = 0; n < 2; ++n)
                #pragma unroll
                for (int r = 0; r < 4; ++r) {
                    int grow = tm * 128 + wr + m * 16 + lg * 4 + r;
                    int gcol = tn * 64 + wc + n * 16 + lr;
                    int b = grow >> 11, ss = grow & 2047, h = gcol >> 6, d = gcol & 63;
                    Vt[((size_t)(b * NUM_HEAD + h) * DK + d) * SEQ + ss] = (__bf16)acc[m][n][r];
                }
    }
}

// ---------------------------------------------------------------------------
// Output projection + residual, 128x64 tiles -> 512 blocks (2/CU).
// ---------------------------------------------------------------------------
__global__ __launch_bounds__(256) void out_gemm(const __bf16* __restrict__ A,
                                                const __bf16* __restrict__ Bw,
                                                const float* __restrict__ residual,
                                                float* __restrict__ out) {
    const int Kd = 1024;
    __shared__ __bf16 As[128][32];
    __shared__ __bf16 Bs[64][32];
    int tm = blockIdx.x >> 4, tn = blockIdx.x & 15;
    int tid = threadIdx.x, lane = tid & 63, wv = tid >> 6;
    int wr = (wv >> 1) * 64, wc = (wv & 1) * 32;
    int lr = lane & 15, lg = lane >> 4;
    int r0 = tid >> 2, c0 = (tid & 3) * 8;

    f32x4 acc[4][2] = {};
    const __bf16* Arow = A  + (size_t)(tm * 128) * Kd;
    const __bf16* Brow = Bw + (size_t)(tn * 64) * Kd;

    for (int kt = 0; kt < Kd; kt += 32) {
        __syncthreads();
        gload_lds16(&Arow[(size_t)r0 * Kd + kt + c0],        &As[r0][c0]);
        gload_lds16(&Arow[(size_t)(r0 + 64) * Kd + kt + c0], &As[r0 + 64][c0]);
        gload_lds16(&Brow[(size_t)r0 * Kd + kt + c0],        &Bs[r0][c0]);
        __syncthreads();
        bf16x8 af[4], bg[2];
        #pragma unroll
        for (int m = 0; m < 4; ++m) af[m] = *(bf16x8*)&As[wr + m * 16 + lr][lg * 8];
        #pragma unroll
        for (int n = 0; n < 2; ++n) bg[n] = *(bf16x8*)&Bs[wc + n * 16 + lr][lg * 8];
        #pragma unroll
        for (int m = 0; m < 4; ++m)
            #pragma unroll
            for (int n = 0; n < 2; ++n)
                acc[m][n] = __builtin_amdgcn_mfma_f32_16x16x32_bf16(af[m], bg[n], acc[m][n], 0, 0, 0);
    }

    #pragma unroll
    for (int m = 0; m < 4; ++m)
        #pragma unroll
        for (int n = 0; n < 2; ++n)
            #pragma unroll
            for (int r = 0; r < 4; ++r) {
                int grow = tm * 128 + wr + m * 16 + lg * 4 + r;
                int gcol = tn * 64 + wc + n * 16 + lr;
                size_t idx = (size_t)grow * DMODEL + gcol;
                out[idx] = acc[m][n][r] + residual[idx];
            }
}

// ---------------------------------------------------------------------------
// Attention, flash-style two-phase, swapped QK^T (32x32x16 MFMA).
// r10 structure + (1) v_permlane32_swap pack (replaces 8 ds_bpermute/tile
// with 2 VALU ops), (2) distance-2 K prefetch in phase B (4 named buffers).
// Grid 2048 blocks (XCD-chunked), 4 waves.
// ---------------------------------------------------------------------------
__global__ __launch_bounds__(256) void attn_kernel(const __bf16* __restrict__ Qp,
                                                   const __bf16* __restrict__ Kp,
                                                   const __bf16* __restrict__ Vt,
                                                   float* __restrict__ attn_out,
                                                   __bf16* __restrict__ out_heads) {
    __shared__ __bf16 ored[4][32][72];   // 18,432 B (bf16 partials)
    __shared__ float  mlred[4][32][2];   //  1,024 B

    int bid = blockIdx.x;
    int wid = (bid & 7) * 256 + (bid >> 3);   // XCD-chunked: each XCD gets 4 heads
    int bh = wid >> 6;
    int qbase = (wid & 63) * 32;
    int tid = threadIdx.x, lane = tid & 63, wv = tid >> 6;
    int l31 = lane & 31, hi = lane >> 5;

    const __bf16* Qh = Qp + ((size_t)bh * SEQ + qbase) * DK;
    const __bf16* Kh = Kp + (size_t)bh * SEQ * DK;
    const __bf16* Vh = Vt + (size_t)bh * DK * SEQ;

    bf16x8 qf[4];
    #pragma unroll
    for (int s = 0; s < 4; ++s)
        qf[s] = *(const bf16x8*)&Qh[(size_t)l31 * DK + s * 16 + hi * 8];

    int kbase = wv * 512;

    auto loadK = [&](bf16x8 (&kf)[4], int k0) {
        #pragma unroll
        for (int s = 0; s < 4; ++s)
            kf[s] = *(const bf16x8*)&Kh[(size_t)(k0 + l31) * DK + s * 16 + hi * 8];
    };

    // ---- Phase A: online max / sum (log2 domain) over this wave's 512 keys ----
    float m = -1e30f, lsum = 0.f;
    auto tileA = [&](const bf16x8 (&kf)[4]) {
        f32x16 dd;
        #pragma unroll
        for (int r = 0; r < 16; ++r) dd[r] = 0.f;
        __builtin_amdgcn_s_setprio(1);
        #pragma unroll
        for (int s = 0; s < 4; ++s)
            dd = __builtin_amdgcn_mfma_f32_32x32x16_bf16(kf[s], qf[s], dd, 0, 0, 0);
        __builtin_amdgcn_s_setprio(0);
        float m8[8];
        #pragma unroll
        for (int r = 0; r < 8; ++r) m8[r] = fmaxf(dd[r], dd[r + 8]);
        #pragma unroll
        for (int r = 0; r < 4; ++r) m8[r] = fmaxf(m8[r], m8[r + 4]);
        float pmax = fmaxf(fmaxf(m8[0], m8[1]), fmaxf(m8[2], m8[3]));
        if (!__all(pmax - m <= 11.0f)) {   // defer-max (log2 domain)
            float nm = fmaxf(m, pmax);
            lsum *= exp2f(m - nm);
            m = nm;
        }
        float es[4] = {0.f, 0.f, 0.f, 0.f};
        #pragma unroll
        for (int r = 0; r < 16; ++r) es[r & 3] += exp2f(dd[r] - m);
        lsum += (es[0] + es[1]) + (es[2] + es[3]);
    };
    {
        bf16x8 kA[4], kB[4];
        loadK(kA, kbase);
        for (int t = 0; t < 16; t += 2) {
            loadK(kB, kbase + (t + 1) * 32);
            tileA(kA);
            if (t + 2 < 16) loadK(kA, kbase + (t + 2) * 32);
            tileA(kB);
        }
    }
    {   // merge interleaved key-halves (lane ^ 32, same q)
        float mo = __shfl_xor(m, 32, 64);
        float lo_ = __shfl_xor(lsum, 32, 64);
        float nm = fmaxf(m, mo);
        lsum = lsum * exp2f(m - nm) + lo_ * exp2f(mo - nm);
        m = nm;
    }
    if (hi == 0) { mlred[wv][l31][0] = m; mlred[wv][l31][1] = lsum; }
    __syncthreads();
    {   // merge across 4 waves (disjoint key ranges)
        float fm = -1e30f;
        #pragma unroll
        for (int w = 0; w < 4; ++w) fm = fmaxf(fm, mlred[w][l31][0]);
        float fl = 0.f;
        #pragma unroll
        for (int w = 0; w < 4; ++w) fl += mlred[w][l31][1] * exp2f(mlred[w][l31][0] - fm);
        m = fm;
        lsum = fl;
    }
    float invl = 1.0f / lsum;

    // ---- Phase B: normalized P, direct global write, PV ----
    float* attn_base = attn_out + ((size_t)bh * SEQ + qbase) * SEQ;
    f32x16 o0, o1;
    #pragma unroll
    for (int r = 0; r < 16; ++r) { o0[r] = 0.f; o1[r] = 0.f; }

    auto tileB = [&](const bf16x8 (&kf)[4], int k0) {
        f32x16 dd;
        #pragma unroll
        for (int r = 0; r < 16; ++r) dd[r] = 0.f;
        __builtin_amdgcn_s_setprio(1);
        #pragma unroll
        for (int s = 0; s < 4; ++s)
            dd = __builtin_amdgcn_mfma_f32_32x32x16_bf16(kf[s], qf[s], dd, 0, 0, 0);
        __builtin_amdgcn_s_setprio(0);

        // hoist V loads (hide L2 latency under exp/pack)
        bf16x8 vf00 = *(const bf16x8*)&Vh[(size_t)(l31)      * SEQ + k0 + hi * 8];
        bf16x8 vf01 = *(const bf16x8*)&Vh[(size_t)(32 + l31) * SEQ + k0 + hi * 8];
        bf16x8 vf10 = *(const bf16x8*)&Vh[(size_t)(l31)      * SEQ + k0 + 16 + hi * 8];
        bf16x8 vf11 = *(const bf16x8*)&Vh[(size_t)(32 + l31) * SEQ + k0 + 16 + hi * 8];

        float p[16];
        #pragma unroll
        for (int r = 0; r < 16; ++r) p[r] = exp2f(dd[r] - m) * invl;

        // direct P write: reg quad q4 = keys k0 + 8*q4 + 4*hi + (0..3), row q=l31
        #pragma unroll
        for (int q4 = 0; q4 < 4; ++q4) {
            f32x4 v4 = {p[4 * q4], p[4 * q4 + 1], p[4 * q4 + 2], p[4 * q4 + 3]};
            *(f32x4*)&attn_base[(size_t)l31 * SEQ + k0 + 8 * q4 + 4 * hi] = v4;
        }

        // pack P to bf16 pair-words: w[i] = keys(reg 2i, 2i+1)
        unsigned int w[8];
        #pragma unroll
        for (int i = 0; i < 8; ++i) {
            union { __bf16 h[2]; unsigned int u; } bw;
            bw.h[0] = (__bf16)p[2 * i];
            bw.h[1] = (__bf16)p[2 * i + 1];
            w[i] = bw.u;
        }
        __builtin_amdgcn_s_setprio(1);
        {   // slot 0 (keys k0..k0+15): permlane32_swap builds both A-frag halves
            unsigned int a0 = w[0], a1 = w[1], a2 = w[2], a3 = w[3];
            asm volatile("v_permlane32_swap_b32 %0, %1" : "+v"(a0), "+v"(a2));
            asm volatile("v_permlane32_swap_b32 %0, %1" : "+v"(a1), "+v"(a3));
            union { unsigned int u[4]; bf16x8 v; } pa;
            pa.u[0] = a0;   // lane<32: w0 ; lane>=32: w2[l-32]
            pa.u[1] = a1;
            pa.u[2] = a2;   // lane<32: w0[l+32] ; lane>=32: w2
            pa.u[3] = a3;
            o0 = __builtin_amdgcn_mfma_f32_32x32x16_bf16(pa.v, vf00, o0, 0, 0, 0);
            o1 = __builtin_amdgcn_mfma_f32_32x32x16_bf16(pa.v, vf01, o1, 0, 0, 0);
        }
        {   // slot 1 (keys k0+16..k0+31)
            unsigned int a0 = w[4], a1 = w[5], a2 = w[6], a3 = w[7];
            asm volatile("v_permlane32_swap_b32 %0, %1" : "+v"(a0), "+v"(a2));
            asm volatile("v_permlane32_swap_b32 %0, %1" : "+v"(a1), "+v"(a3));
            union { unsigned int u[4]; bf16x8 v; } pa;
            pa.u[0] = a0;
            pa.u[1] = a1;
            pa.u[2] = a2;
            pa.u[3] = a3;
            o0 = __builtin_amdgcn_mfma_f32_32x32x16_bf16(pa.v, vf10, o0, 0, 0, 0);
            o1 = __builtin_amdgcn_mfma_f32_32x32x16_bf16(pa.v, vf11, o1, 0, 0, 0);
        }
        __builtin_amdgcn_s_setprio(0);
    };
    {   // distance-2 prefetch, 4 named buffers, unroll-4 rotation
        bf16x8 kA[4], kB[4], kC[4], kD[4];
        loadK(kA, kbase);
        loadK(kB, kbase + 32);
        for (int t = 0; t < 16; t += 4) {
            int k0 = kbase + t * 32;
            if (t + 2 < 16) loadK(kC, kbase + (t + 2) * 32);
            tileB(kA, k0);
            if (t + 3 < 16) loadK(kD, kbase + (t + 3) * 32);
            tileB(kB, k0 + 32);
            if (t + 4 < 16) loadK(kA, kbase + (t + 4) * 32);
            tileB(kC, k0 + 64);
            if (t + 5 < 16) loadK(kB, kbase + (t + 5) * 32);
            tileB(kD, k0 + 96);
        }
    }

    // ---- cross-wave O reduce (bf16 partials), write out_heads ----
    #pragma unroll
    for (int r = 0; r < 16; ++r) {
        int q = (r & 3) + 8 * (r >> 2) + 4 * hi;
        ored[wv][q][l31]      = (__bf16)o0[r];
        ored[wv][q][32 + l31] = (__bf16)o1[r];
    }
    __syncthreads();
    {
        int q = tid >> 3, d0 = (tid & 7) * 8;
        float s[8];
        #pragma unroll
        for (int j = 0; j < 8; ++j) s[j] = 0.f;
        #pragma unroll
        for (int w = 0; w < 4; ++w) {
            bf16x8 pv = *(const bf16x8*)&ored[w][q][d0];
            #pragma unroll
            for (int j = 0; j < 8; ++j) s[j] += (float)pv[j];
        }
        int b = bh >> 4, h = bh & 15;
        bf16x8 ov;
        #pragma unroll
        for (int j = 0; j < 8; ++j) ov[j] = (__bf16)s[j];
        *(bf16x8*)&out_heads[((size_t)(b * SEQ + qbase + q)) * DMODEL + h * DK + d0] = ov;
    }
}

// ---------------------------------------------------------------------------
extern "C" void kernel_launch(void* const* d_in, const int* in_sizes, int n_in,
                              void* d_out, int out_size, void* d_ws, size_t ws_size,
                              hipStream_t stream) {
    const float* query = (const float*)d_in[0];
    const float* key   = (const float*)d_in[1];
    const float* value = (const float*)d_in[2];
    const float* w_q   = (const float*)d_in[3];
    const float* w_k   = (const float*)d_in[4];
    const float* w_v   = (const float*)d_in[5];
    const float* w_o   = (const float*)d_in[6];
    const float* lng   = (const float*)d_in[7];
    const float* lnb   = (const float*)d_in[8];

    char* ws = (char*)d_ws;
    __bf16* qn  = (__bf16*)(ws);                    // 8 MB  LN(query) bf16
    __bf16* kb  = (__bf16*)(ws + ( 8u << 20));      // 8 MB  key bf16
    __bf16* vb  = (__bf16*)(ws + (16u << 20));      // 8 MB  value bf16
    __bf16* wqb = (__bf16*)(ws + (24u << 20));      // 2 MB
    __bf16* wkb = (__bf16*)(ws + (26u << 20));      // 2 MB
    __bf16* wvb = (__bf16*)(ws + (28u << 20));      // 2 MB
    __bf16* wob = (__bf16*)(ws + (30u << 20));      // 2 MB
    __bf16* Qp  = (__bf16*)(ws + (32u << 20));      // 8 MB  [b,h,s,64] (x(1/8)*log2e)
    __bf16* Kp  = (__bf16*)(ws + (40u << 20));      // 8 MB  [b,h,s,64]
    __bf16* Vt  = (__bf16*)(ws + (48u << 20));      // 8 MB  [b,h,64,s']
    __bf16* oh  = (__bf16*)(ws + (56u << 20));      // 8 MB  attention out [4096,1024]

    float* out  = (float*)d_out;
    float* attn = out + (size_t)MROWS * DMODEL;

    ln_cast<<<16384, 256, 0, stream>>>(query, lng, lnb, qn,
                                       key, value, w_q, w_k, w_v, w_o,
                                       kb, vb, wqb, wkb, wvb, wob);

    qkv_proj<<<1536, 256, 0, stream>>>(qn, kb, vb, wqb, wkb, wvb, Qp, Kp, Vt);

    attn_kernel<<<2048, 256, 0, stream>>>(Qp, Kp, Vt, attn, oh);

    out_gemm<<<512, 256, 0, stream>>>(oh, wob, query, out);
}